// Round 1
// baseline (5616.312 us; speedup 1.0000x reference)
//
#include <hip/hip_runtime.h>

#define N_NODES 50000
#define NFEAT   256
#define NGRAPH  64
#define NEDGE   800000

// ---------------- degree / dinv ----------------
__global__ void k_deg_init(float* deg) {
    int i = blockIdx.x * 256 + threadIdx.x;
    if (i < N_NODES) deg[i] = 1.0f;   // self-loop contributes 1 to every node
}

__global__ void k_deg_edges(const int* __restrict__ dst, float* deg) {
    int e = blockIdx.x * 256 + threadIdx.x;
    if (e < NEDGE) unsafeAtomicAdd(&deg[dst[e]], 1.0f);
}

__global__ void k_dinv(float* deg) {
    int i = blockIdx.x * 256 + threadIdx.x;
    if (i < N_NODES) deg[i] = rsqrtf(fmaxf(deg[i], 1e-12f));
}

// ---------------- f32 tiled GEMM: C[M,256] = A[M,256] @ W[256,256] ----------------
// BM=BN=64, BK=16, 256 threads, 4x4 micro-tile per thread.
template <bool RELU_IN>
__global__ __launch_bounds__(256) void k_gemm(const float* __restrict__ A,
                                              const float* __restrict__ W,
                                              float* __restrict__ C, int M) {
    __shared__ float AsT[16][64];  // [k][m]
    __shared__ float Bs[16][64];   // [k][n]
    const int m0 = blockIdx.x * 64, n0 = blockIdx.y * 64;
    const int t = threadIdx.x;
    const int tx = t & 15, ty = t >> 4;
    const int arow = t >> 2, acol = (t & 3) * 4;   // A-tile load: float4 of K per row
    const int brow = t >> 4, bcol = (t & 15) * 4;  // B-tile load
    float acc[4][4] = {};

    for (int k0 = 0; k0 < NFEAT; k0 += 16) {
        float4 av = make_float4(0.f, 0.f, 0.f, 0.f);
        const int gm = m0 + arow;
        if (gm < M) av = *(const float4*)(A + (size_t)gm * NFEAT + k0 + acol);
        if (RELU_IN) {
            av.x = fmaxf(av.x, 0.f); av.y = fmaxf(av.y, 0.f);
            av.z = fmaxf(av.z, 0.f); av.w = fmaxf(av.w, 0.f);
        }
        const float4 bv = *(const float4*)(W + (size_t)(k0 + brow) * NFEAT + n0 + bcol);

        AsT[acol + 0][arow] = av.x;
        AsT[acol + 1][arow] = av.y;
        AsT[acol + 2][arow] = av.z;
        AsT[acol + 3][arow] = av.w;
        *(float4*)&Bs[brow][bcol] = bv;
        __syncthreads();

#pragma unroll
        for (int k = 0; k < 16; ++k) {
            const float4 a4 = *(const float4*)&AsT[k][ty * 4];
            const float4 b4 = *(const float4*)&Bs[k][tx * 4];
            const float a[4] = {a4.x, a4.y, a4.z, a4.w};
            const float b[4] = {b4.x, b4.y, b4.z, b4.w};
#pragma unroll
            for (int i = 0; i < 4; ++i)
#pragma unroll
                for (int j = 0; j < 4; ++j)
                    acc[i][j] = fmaf(a[i], b[j], acc[i][j]);
        }
        __syncthreads();
    }

#pragma unroll
    for (int i = 0; i < 4; ++i) {
        const int gm = m0 + ty * 4 + i;
        if (gm < M)
            *(float4*)(C + (size_t)gm * NFEAT + n0 + tx * 4) =
                make_float4(acc[i][0], acc[i][1], acc[i][2], acc[i][3]);
    }
}

// ---------------- aggregation init: out[i][:] = bias + h[i]*dinv[i]^2 (self-loop) --------
__global__ void k_init_agg(const float* __restrict__ h, const float* __restrict__ bias,
                           const float* __restrict__ dinv, float* __restrict__ out) {
    int idx = blockIdx.x * 256 + threadIdx.x;   // over N*64 float4s
    if (idx >= N_NODES * 64) return;
    const int node = idx >> 6, q = idx & 63;
    const float di = dinv[node];
    const float w = di * di;
    const float4 v = ((const float4*)h)[idx];
    const float4 b = ((const float4*)bias)[q];
    float4 o;
    o.x = b.x + v.x * w; o.y = b.y + v.y * w;
    o.z = b.z + v.z * w; o.w = b.w + v.w * w;
    ((float4*)out)[idx] = o;
}

// ---------------- edge messages: out[dst] += h[src] * dinv[src]*dinv[dst] ----------------
// one 64-lane wave per edge, float4 per lane (256 floats per row)
__global__ __launch_bounds__(256) void k_edge_msg(const float* __restrict__ h,
                                                  const int* __restrict__ src,
                                                  const int* __restrict__ dst,
                                                  const float* __restrict__ dinv,
                                                  float* __restrict__ out) {
    const int e = blockIdx.x * 4 + (threadIdx.x >> 6);
    if (e >= NEDGE) return;
    const int lane = threadIdx.x & 63;
    const int s = src[e], d = dst[e];
    const float norm = dinv[s] * dinv[d];
    const float4 v = ((const float4*)(h + (size_t)s * NFEAT))[lane];
    float* o = out + (size_t)d * NFEAT + lane * 4;
    unsafeAtomicAdd(o + 0, v.x * norm);
    unsafeAtomicAdd(o + 1, v.y * norm);
    unsafeAtomicAdd(o + 2, v.z * norm);
    unsafeAtomicAdd(o + 3, v.w * norm);
}

// ---------------- pooling (batch is sorted): pooled[g][f] += relu(h[n][f]) ----------------
__global__ void k_zero_pooled(float* pooled) {
    int i = blockIdx.x * 256 + threadIdx.x;
    if (i < NGRAPH * NFEAT) pooled[i] = 0.f;
}

__global__ void k_pool(const float* __restrict__ h, const int* __restrict__ batch,
                       float* __restrict__ pooled) {
    const int NPB = 125;                       // 50000/125 = 400 blocks exactly
    const int n0 = blockIdx.x * NPB;
    const int f = threadIdx.x;                 // 256 threads = feature index
    const int n1 = min(n0 + NPB, N_NODES);
    if (n0 >= N_NODES) return;
    int g = batch[n0];
    float acc = 0.f;
    for (int n = n0; n < n1; ++n) {
        const int bg = batch[n];
        if (bg != g) {
            unsafeAtomicAdd(&pooled[g * NFEAT + f], acc);
            acc = 0.f;
            g = bg;
        }
        acc += fmaxf(h[(size_t)n * NFEAT + f], 0.f);
    }
    unsafeAtomicAdd(&pooled[g * NFEAT + f], acc);
}

// ---------------- final head: out[g] = dot(pooled[g], Wout) + bout ----------------
__global__ void k_final(const float* __restrict__ pooled, const float* __restrict__ Wout,
                        const float* __restrict__ bout, float* __restrict__ out) {
    const int g = blockIdx.x, t = threadIdx.x;
    float v = pooled[g * NFEAT + t] * Wout[t];
#pragma unroll
    for (int off = 32; off > 0; off >>= 1) v += __shfl_down(v, off, 64);
    __shared__ float sred[4];
    if ((t & 63) == 0) sred[t >> 6] = v;
    __syncthreads();
    if (t == 0) out[g] = sred[0] + sred[1] + sred[2] + sred[3] + bout[0];
}

extern "C" void kernel_launch(void* const* d_in, const int* in_sizes, int n_in,
                              void* d_out, int out_size, void* d_ws, size_t ws_size,
                              hipStream_t stream) {
    const float* x     = (const float*)d_in[0];
    const int*   ei    = (const int*)d_in[1];
    const int*   batch = (const int*)d_in[2];
    const float* W1    = (const float*)d_in[3];
    const float* b1    = (const float*)d_in[4];
    const float* W2    = (const float*)d_in[5];
    const float* b2    = (const float*)d_in[6];
    const float* Wout  = (const float*)d_in[7];
    const float* bout  = (const float*)d_in[8];
    float* out = (float*)d_out;

    const int* src = ei;            // edge_index[0]
    const int* dst = ei + NEDGE;    // edge_index[1]

    float* buf0   = (float*)d_ws;                          // N*256 f32 (GEMM out)
    float* buf1   = buf0 + (size_t)N_NODES * NFEAT;        // N*256 f32 (agg out)
    float* deg    = buf1 + (size_t)N_NODES * NFEAT;        // N f32 (deg -> dinv)
    float* pooled = deg + N_NODES;                         // 64*256 f32

    const dim3 gemm_grid((N_NODES + 63) / 64, NFEAT / 64);

    // degrees
    k_deg_init<<<(N_NODES + 255) / 256, 256, 0, stream>>>(deg);
    k_deg_edges<<<(NEDGE + 255) / 256, 256, 0, stream>>>(dst, deg);
    k_dinv<<<(N_NODES + 255) / 256, 256, 0, stream>>>(deg);

    // layer 1
    k_gemm<false><<<gemm_grid, 256, 0, stream>>>(x, W1, buf0, N_NODES);
    k_init_agg<<<(N_NODES * 64 + 255) / 256, 256, 0, stream>>>(buf0, b1, deg, buf1);
    k_edge_msg<<<(NEDGE + 3) / 4, 256, 0, stream>>>(buf0, src, dst, deg, buf1);

    // layer 2 (relu of layer-1 output fused into GEMM A-load)
    k_gemm<true><<<gemm_grid, 256, 0, stream>>>(buf1, W2, buf0, N_NODES);
    k_init_agg<<<(N_NODES * 64 + 255) / 256, 256, 0, stream>>>(buf0, b2, deg, buf1);
    k_edge_msg<<<(NEDGE + 3) / 4, 256, 0, stream>>>(buf0, src, dst, deg, buf1);

    // pooling (relu fused into read) + head
    k_zero_pooled<<<(NGRAPH * NFEAT + 255) / 256, 256, 0, stream>>>(pooled);
    k_pool<<<400, 256, 0, stream>>>(buf1, batch, pooled);
    k_final<<<NGRAPH, 256, 0, stream>>>(pooled, Wout, bout, out);
}

// Round 2
// 666.351 us; speedup vs baseline: 8.4285x; 8.4285x over previous
//
#include <hip/hip_runtime.h>

#define N_NODES 50000
#define NFEAT   256
#define NGRAPH  64
#define NEDGE   800000

// ================= CSR build =================
__global__ void k_zero_int(int* p, int n) {
    int i = blockIdx.x * 256 + threadIdx.x;
    if (i < n) p[i] = 0;
}

__global__ void k_count(const int* __restrict__ dst, int* __restrict__ cnt) {
    int e = blockIdx.x * 256 + threadIdx.x;
    if (e < NEDGE) atomicAdd(&cnt[dst[e]], 1);
}

// single-block exclusive scan of cnt[0..N) -> row_start[0..N], row_start[N]=total
#define SCAN_T 1024
__global__ __launch_bounds__(SCAN_T) void k_scan(const int* __restrict__ cnt,
                                                 int* __restrict__ row_start) {
    __shared__ int sums[SCAN_T];
    const int t = threadIdx.x;
    const int per = (N_NODES + SCAN_T - 1) / SCAN_T;  // 49
    const int base = t * per;
    int local = 0;
    for (int i = 0; i < per; ++i) {
        int idx = base + i;
        if (idx < N_NODES) local += cnt[idx];
    }
    sums[t] = local;
    __syncthreads();
    for (int off = 1; off < SCAN_T; off <<= 1) {
        int u = (t >= off) ? sums[t - off] : 0;
        __syncthreads();
        if (t >= off) sums[t] += u;
        __syncthreads();
    }
    int run = sums[t] - local;  // exclusive prefix of this thread's chunk
    for (int i = 0; i < per; ++i) {
        int idx = base + i;
        if (idx < N_NODES) { row_start[idx] = run; run += cnt[idx]; }
    }
    if (t == SCAN_T - 1) row_start[N_NODES] = run;
}

__global__ void k_copy_cursor(const int* __restrict__ row_start, int* __restrict__ cursor) {
    int i = blockIdx.x * 256 + threadIdx.x;
    if (i < N_NODES) cursor[i] = row_start[i];
}

__global__ void k_place(const int* __restrict__ src, const int* __restrict__ dst,
                        int* __restrict__ cursor, int* __restrict__ csr_src) {
    int e = blockIdx.x * 256 + threadIdx.x;
    if (e < NEDGE) {
        int d = dst[e];
        int pos = atomicAdd(&cursor[d], 1);
        csr_src[pos] = src[e];
    }
}

__global__ void k_dinv(const int* __restrict__ cnt, float* __restrict__ dinv) {
    int i = blockIdx.x * 256 + threadIdx.x;
    if (i < N_NODES) dinv[i] = rsqrtf((float)cnt[i] + 1.0f);  // +1 self-loop
}

// ================= f32 tiled GEMM: C[M,256] = A[M,256] @ W[256,256] =================
template <bool RELU_IN>
__global__ __launch_bounds__(256) void k_gemm(const float* __restrict__ A,
                                              const float* __restrict__ W,
                                              float* __restrict__ C, int M) {
    __shared__ float AsT[16][64];  // [k][m]
    __shared__ float Bs[16][64];   // [k][n]
    const int m0 = blockIdx.x * 64, n0 = blockIdx.y * 64;
    const int t = threadIdx.x;
    const int tx = t & 15, ty = t >> 4;
    const int arow = t >> 2, acol = (t & 3) * 4;
    const int brow = t >> 4, bcol = (t & 15) * 4;
    float acc[4][4] = {};

    for (int k0 = 0; k0 < NFEAT; k0 += 16) {
        float4 av = make_float4(0.f, 0.f, 0.f, 0.f);
        const int gm = m0 + arow;
        if (gm < M) av = *(const float4*)(A + (size_t)gm * NFEAT + k0 + acol);
        if (RELU_IN) {
            av.x = fmaxf(av.x, 0.f); av.y = fmaxf(av.y, 0.f);
            av.z = fmaxf(av.z, 0.f); av.w = fmaxf(av.w, 0.f);
        }
        const float4 bv = *(const float4*)(W + (size_t)(k0 + brow) * NFEAT + n0 + bcol);

        AsT[acol + 0][arow] = av.x;
        AsT[acol + 1][arow] = av.y;
        AsT[acol + 2][arow] = av.z;
        AsT[acol + 3][arow] = av.w;
        *(float4*)&Bs[brow][bcol] = bv;
        __syncthreads();

#pragma unroll
        for (int k = 0; k < 16; ++k) {
            const float4 a4 = *(const float4*)&AsT[k][ty * 4];
            const float4 b4 = *(const float4*)&Bs[k][tx * 4];
            const float a[4] = {a4.x, a4.y, a4.z, a4.w};
            const float b[4] = {b4.x, b4.y, b4.z, b4.w};
#pragma unroll
            for (int i = 0; i < 4; ++i)
#pragma unroll
                for (int j = 0; j < 4; ++j)
                    acc[i][j] = fmaf(a[i], b[j], acc[i][j]);
        }
        __syncthreads();
    }

#pragma unroll
    for (int i = 0; i < 4; ++i) {
        const int gm = m0 + ty * 4 + i;
        if (gm < M)
            *(float4*)(C + (size_t)gm * NFEAT + n0 + tx * 4) =
                make_float4(acc[i][0], acc[i][1], acc[i][2], acc[i][3]);
    }
}

// ================= aggregation: one wave per dst node, register accumulation =========
// out[d] = bias + h[d]*dinv[d]^2 + sum_{s in row(d)} h[s]*dinv[s]*dinv[d]
__global__ __launch_bounds__(256) void k_aggregate(const float* __restrict__ h,
                                                   const int* __restrict__ row_start,
                                                   const int* __restrict__ csr_src,
                                                   const float* __restrict__ dinv,
                                                   const float* __restrict__ bias,
                                                   float* __restrict__ out) {
    const int node = blockIdx.x * 4 + (threadIdx.x >> 6);
    if (node >= N_NODES) return;
    const int lane = threadIdx.x & 63;
    const float dd = dinv[node];
    const float wself = dd * dd;
    const float4 b = ((const float4*)bias)[lane];
    const float4 self = ((const float4*)(h + (size_t)node * NFEAT))[lane];
    float4 acc;
    acc.x = b.x + self.x * wself;
    acc.y = b.y + self.y * wself;
    acc.z = b.z + self.z * wself;
    acc.w = b.w + self.w * wself;

    const int s0 = row_start[node], s1 = row_start[node + 1];
    for (int j = s0; j < s1; ++j) {
        const int s = csr_src[j];                // wave-uniform broadcast load
        const float nw = dinv[s] * dd;
        const float4 v = ((const float4*)(h + (size_t)s * NFEAT))[lane];
        acc.x = fmaf(v.x, nw, acc.x);
        acc.y = fmaf(v.y, nw, acc.y);
        acc.z = fmaf(v.z, nw, acc.z);
        acc.w = fmaf(v.w, nw, acc.w);
    }
    ((float4*)(out + (size_t)node * NFEAT))[lane] = acc;
}

// ================= pooling (batch sorted) + head =================
__global__ void k_zero_f(float* p, int n) {
    int i = blockIdx.x * 256 + threadIdx.x;
    if (i < n) p[i] = 0.f;
}

__global__ void k_pool(const float* __restrict__ h, const int* __restrict__ batch,
                       float* __restrict__ pooled) {
    const int NPB = 125;
    const int n0 = blockIdx.x * NPB;
    const int f = threadIdx.x;
    const int n1 = min(n0 + NPB, N_NODES);
    if (n0 >= N_NODES) return;
    int g = batch[n0];
    float acc = 0.f;
    for (int n = n0; n < n1; ++n) {
        const int bg = batch[n];
        if (bg != g) {
            unsafeAtomicAdd(&pooled[g * NFEAT + f], acc);
            acc = 0.f;
            g = bg;
        }
        acc += fmaxf(h[(size_t)n * NFEAT + f], 0.f);
    }
    unsafeAtomicAdd(&pooled[g * NFEAT + f], acc);
}

__global__ void k_final(const float* __restrict__ pooled, const float* __restrict__ Wout,
                        const float* __restrict__ bout, float* __restrict__ out) {
    const int g = blockIdx.x, t = threadIdx.x;
    float v = pooled[g * NFEAT + t] * Wout[t];
#pragma unroll
    for (int off = 32; off > 0; off >>= 1) v += __shfl_down(v, off, 64);
    __shared__ float sred[4];
    if ((t & 63) == 0) sred[t >> 6] = v;
    __syncthreads();
    if (t == 0) out[g] = sred[0] + sred[1] + sred[2] + sred[3] + bout[0];
}

extern "C" void kernel_launch(void* const* d_in, const int* in_sizes, int n_in,
                              void* d_out, int out_size, void* d_ws, size_t ws_size,
                              hipStream_t stream) {
    const float* x     = (const float*)d_in[0];
    const int*   ei    = (const int*)d_in[1];
    const int*   batch = (const int*)d_in[2];
    const float* W1    = (const float*)d_in[3];
    const float* b1    = (const float*)d_in[4];
    const float* W2    = (const float*)d_in[5];
    const float* b2    = (const float*)d_in[6];
    const float* Wout  = (const float*)d_in[7];
    const float* bout  = (const float*)d_in[8];
    float* out = (float*)d_out;

    const int* src = ei;
    const int* dst = ei + NEDGE;

    float* buf0      = (float*)d_ws;                        // N*256 f32
    float* buf1      = buf0 + (size_t)N_NODES * NFEAT;      // N*256 f32
    float* dinv      = buf1 + (size_t)N_NODES * NFEAT;      // N f32
    float* pooled    = dinv + N_NODES;                      // 64*256 f32
    int*   cnt       = (int*)(pooled + NGRAPH * NFEAT);     // N int
    int*   row_start = cnt + N_NODES;                       // N+1 int
    int*   cursor    = row_start + N_NODES + 1;             // N int
    int*   csr_src   = cursor + N_NODES;                    // NEDGE int

    const dim3 gemm_grid((N_NODES + 63) / 64, NFEAT / 64);
    const int nblk_nodes = (N_NODES + 255) / 256;
    const int nblk_edges = (NEDGE + 255) / 256;

    // ---- CSR build (once, reused by both layers) ----
    k_zero_int<<<nblk_nodes, 256, 0, stream>>>(cnt, N_NODES);
    k_count<<<nblk_edges, 256, 0, stream>>>(dst, cnt);
    k_scan<<<1, SCAN_T, 0, stream>>>(cnt, row_start);
    k_copy_cursor<<<nblk_nodes, 256, 0, stream>>>(row_start, cursor);
    k_place<<<nblk_edges, 256, 0, stream>>>(src, dst, cursor, csr_src);
    k_dinv<<<nblk_nodes, 256, 0, stream>>>(cnt, dinv);

    // ---- layer 1 ----
    k_gemm<false><<<gemm_grid, 256, 0, stream>>>(x, W1, buf0, N_NODES);
    k_aggregate<<<(N_NODES + 3) / 4, 256, 0, stream>>>(buf0, row_start, csr_src, dinv, b1, buf1);

    // ---- layer 2 (relu fused into GEMM A-load) ----
    k_gemm<true><<<gemm_grid, 256, 0, stream>>>(buf1, W2, buf0, N_NODES);
    k_aggregate<<<(N_NODES + 3) / 4, 256, 0, stream>>>(buf0, row_start, csr_src, dinv, b2, buf1);

    // ---- pooling (relu fused) + head ----
    k_zero_f<<<(NGRAPH * NFEAT + 255) / 256, 256, 0, stream>>>(pooled, NGRAPH * NFEAT);
    k_pool<<<400, 256, 0, stream>>>(buf1, batch, pooled);
    k_final<<<NGRAPH, 256, 0, stream>>>(pooled, Wout, bout, out);
}

// Round 3
// 622.792 us; speedup vs baseline: 9.0180x; 1.0699x over previous
//
#include <hip/hip_runtime.h>
#include <hip/hip_fp16.h>

#define N_NODES 50000
#define NFEAT   256
#define NGRAPH  64
#define NEDGE   800000

typedef __attribute__((ext_vector_type(8))) short short8;
typedef __attribute__((ext_vector_type(4))) float f32x4;

static __device__ __forceinline__ unsigned short f2bf(float f) {
    unsigned int u = __float_as_uint(f);
    unsigned int r = (u + 0x7fff + ((u >> 16) & 1)) >> 16;  // RTN-even
    return (unsigned short)r;
}
static __device__ __forceinline__ float bf2f(unsigned short b) {
    return __uint_as_float(((unsigned int)b) << 16);
}

// ================= CSR build =================
__global__ void k_zero_int(int* p, int n) {
    int i = blockIdx.x * 256 + threadIdx.x;
    if (i < n) p[i] = 0;
}

__global__ void k_count(const int* __restrict__ dst, int* __restrict__ cnt) {
    int e = blockIdx.x * 256 + threadIdx.x;
    if (e < NEDGE) atomicAdd(&cnt[dst[e]], 1);
}

// single-block scan: row_start (exclusive), cnt<-cursor init, dinv
#define SCAN_T 1024
__global__ __launch_bounds__(SCAN_T) void k_scan(int* __restrict__ cnt,
                                                 int* __restrict__ row_start,
                                                 float* __restrict__ dinv) {
    __shared__ int sums[SCAN_T];
    const int t = threadIdx.x;
    const int per = (N_NODES + SCAN_T - 1) / SCAN_T;  // 49
    const int base = t * per;
    int local = 0;
    for (int i = 0; i < per; ++i) {
        int idx = base + i;
        if (idx < N_NODES) local += cnt[idx];
    }
    sums[t] = local;
    __syncthreads();
    for (int off = 1; off < SCAN_T; off <<= 1) {
        int u = (t >= off) ? sums[t - off] : 0;
        __syncthreads();
        if (t >= off) sums[t] += u;
        __syncthreads();
    }
    int run = sums[t] - local;
    for (int i = 0; i < per; ++i) {
        int idx = base + i;
        if (idx < N_NODES) {
            int c = cnt[idx];
            row_start[idx] = run;
            cnt[idx] = run;                         // cursor init (alias)
            dinv[idx] = rsqrtf((float)c + 1.0f);    // +1 self-loop
            run += c;
        }
    }
    if (t == SCAN_T - 1) row_start[N_NODES] = run;
}

// place edges: csr[pos] = {norm_f16 <<16 | src}
__global__ void k_place(const int* __restrict__ src, const int* __restrict__ dst,
                        int* __restrict__ cursor, const float* __restrict__ dinv,
                        unsigned int* __restrict__ csr) {
    int e = blockIdx.x * 256 + threadIdx.x;
    if (e < NEDGE) {
        int s = src[e], d = dst[e];
        float norm = dinv[s] * dinv[d];
        int pos = atomicAdd(&cursor[d], 1);
        unsigned short hb = __half_as_ushort(__float2half(norm));
        csr[pos] = ((unsigned int)hb << 16) | (unsigned int)s;
    }
}

// ================= W prep: W[k][n] f32 -> Wt_hi/Wt_lo [n][k] bf16 =================
__global__ void k_prep_w(const float* __restrict__ W1, const float* __restrict__ W2,
                         unsigned short* __restrict__ w1hi, unsigned short* __restrict__ w1lo,
                         unsigned short* __restrict__ w2hi, unsigned short* __restrict__ w2lo) {
    const int l = blockIdx.x >> 8;                 // layer
    const int idx = (blockIdx.x & 255) * 256 + threadIdx.x;  // 0..65535
    const int n = idx >> 8, k = idx & 255;
    const float* W = l ? W2 : W1;
    unsigned short* whi = l ? w2hi : w1hi;
    unsigned short* wlo = l ? w2lo : w1lo;
    const float w = W[k * 256 + n];
    unsigned short hi = f2bf(w);
    unsigned short lo = f2bf(w - bf2f(hi));
    whi[n * 256 + k] = hi;
    wlo[n * 256 + k] = lo;
}

// ================= MFMA split-bf16 GEMM: C[M,256] = A[M,256] @ W =================
// BM=128, BN=128 (grid.y=2 halves), 4 waves 2x2, per wave 4x4 frags of 16x16x32.
template <bool RELU_IN>
__global__ __launch_bounds__(256) void k_gemm_mfma(const float* __restrict__ A,
                                                   const unsigned short* __restrict__ Wthi,
                                                   const unsigned short* __restrict__ Wtlo,
                                                   float* __restrict__ C, int M) {
    __shared__ short wt[2][2][128][48];  // [dbuf][hi/lo][n][k(32)+pad16]
    const int t = threadIdx.x;
    const int m0 = blockIdx.x * 128;
    const int nb = blockIdx.y * 128;
    const int w = t >> 6, lane = t & 63;
    const int wr = w >> 1, wc = w & 1;
    const int lr = lane & 15, g = lane >> 4;

    f32x4 acc[4][4] = {};

    // staging: 256 threads, each 2 rows x 16B per plane
    const int seg = t & 3, nr = t >> 2;
#define STAGE(BUF, KS)                                                              \
    {                                                                               \
        _Pragma("unroll") for (int rep = 0; rep < 2; ++rep) {                       \
            const int n = nr + rep * 64;                                            \
            const int gidx = (nb + n) * 256 + (KS) * 32 + seg * 8;                  \
            *(short8*)&wt[BUF][0][n][seg * 8] = *(const short8*)&Wthi[gidx];        \
            *(short8*)&wt[BUF][1][n][seg * 8] = *(const short8*)&Wtlo[gidx];        \
        }                                                                           \
    }

    STAGE(0, 0)
    int buf = 0;

    for (int ks = 0; ks < 8; ++ks) {
        __syncthreads();
        if (ks < 7) STAGE(buf ^ 1, ks + 1)

        short8 bh[4], bl[4];
#pragma unroll
        for (int ni = 0; ni < 4; ++ni) {
            const int n = wc * 64 + ni * 16 + lr;
            bh[ni] = *(const short8*)&wt[buf][0][n][g * 8];
            bl[ni] = *(const short8*)&wt[buf][1][n][g * 8];
        }

        short8 ah[4], al[4];
#pragma unroll
        for (int mi = 0; mi < 4; ++mi) {
            const int row = m0 + wr * 64 + mi * 16 + lr;
            float av[8] = {0.f, 0.f, 0.f, 0.f, 0.f, 0.f, 0.f, 0.f};
            if (row < M) {
                const float* ap = A + (size_t)row * 256 + ks * 32 + g * 8;
                const float4 p0 = *(const float4*)ap;
                const float4 p1 = *(const float4*)(ap + 4);
                av[0] = p0.x; av[1] = p0.y; av[2] = p0.z; av[3] = p0.w;
                av[4] = p1.x; av[5] = p1.y; av[6] = p1.z; av[7] = p1.w;
            }
#pragma unroll
            for (int i = 0; i < 8; ++i) {
                float v = RELU_IN ? fmaxf(av[i], 0.f) : av[i];
                unsigned short hi = f2bf(v);
                ah[mi][i] = (short)hi;
                al[mi][i] = (short)f2bf(v - bf2f(hi));
            }
        }

#pragma unroll
        for (int mi = 0; mi < 4; ++mi)
#pragma unroll
            for (int ni = 0; ni < 4; ++ni) {
                acc[mi][ni] = __builtin_amdgcn_mfma_f32_16x16x32_bf16(ah[mi], bh[ni], acc[mi][ni], 0, 0, 0);
                acc[mi][ni] = __builtin_amdgcn_mfma_f32_16x16x32_bf16(ah[mi], bl[ni], acc[mi][ni], 0, 0, 0);
                acc[mi][ni] = __builtin_amdgcn_mfma_f32_16x16x32_bf16(al[mi], bh[ni], acc[mi][ni], 0, 0, 0);
            }
        buf ^= 1;
    }
#undef STAGE

#pragma unroll
    for (int mi = 0; mi < 4; ++mi) {
        const int r0 = m0 + wr * 64 + mi * 16 + g * 4;
#pragma unroll
        for (int ni = 0; ni < 4; ++ni) {
            const int col = nb + wc * 64 + ni * 16 + lr;
#pragma unroll
            for (int r = 0; r < 4; ++r) {
                if (r0 + r < M) C[(size_t)(r0 + r) * 256 + col] = acc[mi][ni][r];
            }
        }
    }
}

// ================= aggregation: one wave per dst node =================
__global__ __launch_bounds__(256) void k_aggregate(const float* __restrict__ h,
                                                   const int* __restrict__ row_start,
                                                   const unsigned int* __restrict__ csr,
                                                   const float* __restrict__ dinv,
                                                   const float* __restrict__ bias,
                                                   float* __restrict__ out) {
    const int node = blockIdx.x * 4 + (threadIdx.x >> 6);
    if (node >= N_NODES) return;
    const int lane = threadIdx.x & 63;
    const float dd = dinv[node];
    const float wself = dd * dd;
    const float4 b = ((const float4*)bias)[lane];
    const float4 self = ((const float4*)(h + (size_t)node * NFEAT))[lane];
    float4 acc;
    acc.x = b.x + self.x * wself;
    acc.y = b.y + self.y * wself;
    acc.z = b.z + self.z * wself;
    acc.w = b.w + self.w * wself;

    const int s0 = row_start[node], s1 = row_start[node + 1];
    const unsigned int* row = csr + s0;
    const int n = s1 - s0;
    int j = 0;
    for (; j + 3 < n; j += 4) {
        const unsigned int e0 = row[j], e1 = row[j + 1], e2 = row[j + 2], e3 = row[j + 3];
        const float4 v0 = ((const float4*)(h + (size_t)(e0 & 0xffff) * NFEAT))[lane];
        const float4 v1 = ((const float4*)(h + (size_t)(e1 & 0xffff) * NFEAT))[lane];
        const float4 v2 = ((const float4*)(h + (size_t)(e2 & 0xffff) * NFEAT))[lane];
        const float4 v3 = ((const float4*)(h + (size_t)(e3 & 0xffff) * NFEAT))[lane];
        const float w0 = __half2float(__ushort_as_half((unsigned short)(e0 >> 16)));
        const float w1 = __half2float(__ushort_as_half((unsigned short)(e1 >> 16)));
        const float w2 = __half2float(__ushort_as_half((unsigned short)(e2 >> 16)));
        const float w3 = __half2float(__ushort_as_half((unsigned short)(e3 >> 16)));
        acc.x += v0.x * w0 + v1.x * w1 + v2.x * w2 + v3.x * w3;
        acc.y += v0.y * w0 + v1.y * w1 + v2.y * w2 + v3.y * w3;
        acc.z += v0.z * w0 + v1.z * w1 + v2.z * w2 + v3.z * w3;
        acc.w += v0.w * w0 + v1.w * w1 + v2.w * w2 + v3.w * w3;
    }
    for (; j < n; ++j) {
        const unsigned int e = row[j];
        const float4 v = ((const float4*)(h + (size_t)(e & 0xffff) * NFEAT))[lane];
        const float wn = __half2float(__ushort_as_half((unsigned short)(e >> 16)));
        acc.x = fmaf(v.x, wn, acc.x);
        acc.y = fmaf(v.y, wn, acc.y);
        acc.z = fmaf(v.z, wn, acc.z);
        acc.w = fmaf(v.w, wn, acc.w);
    }
    ((float4*)(out + (size_t)node * NFEAT))[lane] = acc;
}

// ================= pooling (batch sorted) + head =================
__global__ void k_zero_f(float* p, int n) {
    int i = blockIdx.x * 256 + threadIdx.x;
    if (i < n) p[i] = 0.f;
}

__global__ void k_pool(const float* __restrict__ h, const int* __restrict__ batch,
                       float* __restrict__ pooled) {
    const int NPB = 125;
    const int n0 = blockIdx.x * NPB;
    const int f = threadIdx.x;
    const int n1 = min(n0 + NPB, N_NODES);
    if (n0 >= N_NODES) return;
    int g = batch[n0];
    float acc = 0.f;
    for (int n = n0; n < n1; ++n) {
        const int bg = batch[n];
        if (bg != g) {
            unsafeAtomicAdd(&pooled[g * NFEAT + f], acc);
            acc = 0.f;
            g = bg;
        }
        acc += fmaxf(h[(size_t)n * NFEAT + f], 0.f);
    }
    unsafeAtomicAdd(&pooled[g * NFEAT + f], acc);
}

__global__ void k_final(const float* __restrict__ pooled, const float* __restrict__ Wout,
                        const float* __restrict__ bout, float* __restrict__ out) {
    const int g = blockIdx.x, t = threadIdx.x;
    float v = pooled[g * NFEAT + t] * Wout[t];
#pragma unroll
    for (int off = 32; off > 0; off >>= 1) v += __shfl_down(v, off, 64);
    __shared__ float sred[4];
    if ((t & 63) == 0) sred[t >> 6] = v;
    __syncthreads();
    if (t == 0) out[g] = sred[0] + sred[1] + sred[2] + sred[3] + bout[0];
}

extern "C" void kernel_launch(void* const* d_in, const int* in_sizes, int n_in,
                              void* d_out, int out_size, void* d_ws, size_t ws_size,
                              hipStream_t stream) {
    const float* x     = (const float*)d_in[0];
    const int*   ei    = (const int*)d_in[1];
    const int*   batch = (const int*)d_in[2];
    const float* W1    = (const float*)d_in[3];
    const float* b1    = (const float*)d_in[4];
    const float* W2    = (const float*)d_in[5];
    const float* b2    = (const float*)d_in[6];
    const float* Wout  = (const float*)d_in[7];
    const float* bout  = (const float*)d_in[8];
    float* out = (float*)d_out;

    const int* srcp = ei;
    const int* dstp = ei + NEDGE;

    float* buf0      = (float*)d_ws;                        // 12.8M f32
    float* buf1      = buf0 + (size_t)N_NODES * NFEAT;      // 12.8M f32
    float* dinv      = buf1 + (size_t)N_NODES * NFEAT;      // 50000
    float* pooled    = dinv + N_NODES;                      // 16384
    int*   cnt       = (int*)(pooled + NGRAPH * NFEAT);     // 50000 (doubles as cursor)
    int*   row_start = cnt + N_NODES;                       // 50001
    unsigned int* csr = (unsigned int*)(row_start + N_NODES + 2);  // 800000 (8B-ish align)
    unsigned short* w1hi = (unsigned short*)(csr + NEDGE);  // 65536 each
    unsigned short* w1lo = w1hi + 65536;
    unsigned short* w2hi = w1lo + 65536;
    unsigned short* w2lo = w2hi + 65536;

    const int nblk_nodes = (N_NODES + 255) / 256;
    const int nblk_edges = (NEDGE + 255) / 256;

    // ---- CSR build ----
    k_zero_int<<<nblk_nodes, 256, 0, stream>>>(cnt, N_NODES);
    k_count<<<nblk_edges, 256, 0, stream>>>(dstp, cnt);
    k_scan<<<1, SCAN_T, 0, stream>>>(cnt, row_start, dinv);
    k_place<<<nblk_edges, 256, 0, stream>>>(srcp, dstp, cnt, dinv, csr);

    // ---- W decomposition ----
    k_prep_w<<<512, 256, 0, stream>>>(W1, W2, w1hi, w1lo, w2hi, w2lo);

    const dim3 ggrid((N_NODES + 127) / 128, 2);

    // ---- layer 1 ----
    k_gemm_mfma<false><<<ggrid, 256, 0, stream>>>(x, w1hi, w1lo, buf0, N_NODES);
    k_aggregate<<<(N_NODES + 3) / 4, 256, 0, stream>>>(buf0, row_start, csr, dinv, b1, buf1);

    // ---- layer 2 ----
    k_gemm_mfma<true><<<ggrid, 256, 0, stream>>>(buf1, w2hi, w2lo, buf0, N_NODES);
    k_aggregate<<<(N_NODES + 3) / 4, 256, 0, stream>>>(buf0, row_start, csr, dinv, b2, buf1);

    // ---- pooling + head ----
    k_zero_f<<<(NGRAPH * NFEAT + 255) / 256, 256, 0, stream>>>(pooled, NGRAPH * NFEAT);
    k_pool<<<400, 256, 0, stream>>>(buf1, batch, pooled);
    k_final<<<NGRAPH, 256, 0, stream>>>(pooled, Wout, bout, out);
}

// Round 4
// 476.782 us; speedup vs baseline: 11.7796x; 1.3062x over previous
//
#include <hip/hip_runtime.h>
#include <hip/hip_fp16.h>

#define N_NODES 50000
#define NFEAT   256
#define NGRAPH  64
#define NEDGE   800000
#define NBLK_SCAN 196  // ceil(50000/256)

typedef __attribute__((ext_vector_type(8))) short short8;
typedef __attribute__((ext_vector_type(4))) float f32x4;

static __device__ __forceinline__ unsigned short f2bf(float f) {
    unsigned int u = __float_as_uint(f);
    unsigned int r = (u + 0x7fff + ((u >> 16) & 1)) >> 16;  // RTN-even
    return (unsigned short)r;
}
static __device__ __forceinline__ float bf2f(unsigned short b) {
    return __uint_as_float(((unsigned int)b) << 16);
}

// ================= CSR build =================
__global__ void k_zero_int(int* p, int n) {
    int i = blockIdx.x * 256 + threadIdx.x;
    if (i < n) p[i] = 0;
}

__global__ void k_count(const int* __restrict__ dst, int* __restrict__ cnt) {
    int e = blockIdx.x * 256 + threadIdx.x;
    if (e < NEDGE) atomicAdd(&cnt[dst[e]], 1);
}

// --- hierarchical scan, phase 1: block-local exclusive scan + block sums ---
__global__ __launch_bounds__(256) void k_scan1(const int* __restrict__ cnt,
                                               int* __restrict__ row_start,
                                               int* __restrict__ bsum) {
    const int t = threadIdx.x, i = blockIdx.x * 256 + t;
    const int lane = t & 63, w = t >> 6;
    const int c = (i < N_NODES) ? cnt[i] : 0;
    int incl = c;
#pragma unroll
    for (int off = 1; off < 64; off <<= 1) {
        int u = __shfl_up(incl, off, 64);
        if (lane >= off) incl += u;
    }
    __shared__ int wtot[4];
    if (lane == 63) wtot[w] = incl;
    __syncthreads();
    int wbase = 0;
#pragma unroll
    for (int k = 0; k < 4; ++k) wbase += (k < w) ? wtot[k] : 0;
    if (i < N_NODES) row_start[i] = wbase + incl - c;  // block-local exclusive
    if (t == 255) bsum[blockIdx.x] = wbase + incl;     // block total
}

// --- phase 2: single tiny block scans the block sums (exclusive, in place) ---
__global__ __launch_bounds__(256) void k_scan2(int* __restrict__ bsum) {
    const int t = threadIdx.x, lane = t & 63, w = t >> 6;
    const int c = (t < NBLK_SCAN) ? bsum[t] : 0;
    int incl = c;
#pragma unroll
    for (int off = 1; off < 64; off <<= 1) {
        int u = __shfl_up(incl, off, 64);
        if (lane >= off) incl += u;
    }
    __shared__ int wtot[4];
    if (lane == 63) wtot[w] = incl;
    __syncthreads();
    int wbase = 0;
#pragma unroll
    for (int k = 0; k < 4; ++k) wbase += (k < w) ? wtot[k] : 0;
    if (t < NBLK_SCAN) bsum[t] = wbase + incl - c;  // exclusive block offset
}

// --- phase 3: finalize row_start, init cursor (aliases cnt), dinv ---
__global__ void k_scan3(int* __restrict__ row_start, const int* __restrict__ bsum,
                        int* __restrict__ cnt_cursor, float* __restrict__ dinv) {
    const int i = blockIdx.x * 256 + threadIdx.x;
    if (i >= N_NODES) return;
    const int c = cnt_cursor[i];
    const int start = row_start[i] + bsum[blockIdx.x];
    row_start[i] = start;
    cnt_cursor[i] = start;
    dinv[i] = rsqrtf((float)c + 1.0f);  // +1 self-loop
    if (i == 0) row_start[N_NODES] = NEDGE;
}

// place edges: csr[pos] = {norm_f16 <<16 | src}
__global__ void k_place(const int* __restrict__ src, const int* __restrict__ dst,
                        int* __restrict__ cursor, const float* __restrict__ dinv,
                        unsigned int* __restrict__ csr) {
    int e = blockIdx.x * 256 + threadIdx.x;
    if (e < NEDGE) {
        int s = src[e], d = dst[e];
        float norm = dinv[s] * dinv[d];
        int pos = atomicAdd(&cursor[d], 1);
        unsigned short hb = __half_as_ushort(__float2half(norm));
        csr[pos] = ((unsigned int)hb << 16) | (unsigned int)s;
    }
}

// ================= W prep: W[k][n] f32 -> Wt_hi/Wt_lo [n][k] bf16 =================
__global__ void k_prep_w(const float* __restrict__ W1, const float* __restrict__ W2,
                         unsigned short* __restrict__ w1hi, unsigned short* __restrict__ w1lo,
                         unsigned short* __restrict__ w2hi, unsigned short* __restrict__ w2lo) {
    const int l = blockIdx.x >> 8;
    const int idx = (blockIdx.x & 255) * 256 + threadIdx.x;
    const int n = idx >> 8, k = idx & 255;
    const float* W = l ? W2 : W1;
    unsigned short* whi = l ? w2hi : w1hi;
    unsigned short* wlo = l ? w2lo : w1lo;
    const float w = W[k * 256 + n];
    unsigned short hi = f2bf(w);
    unsigned short lo = f2bf(w - bf2f(hi));
    whi[n * 256 + k] = hi;
    wlo[n * 256 + k] = lo;
}

// ================= MFMA split-bf16 GEMM: C[M,256] = A[M,256] @ W =================
template <bool RELU_IN>
__global__ __launch_bounds__(256) void k_gemm_mfma(const float* __restrict__ A,
                                                   const unsigned short* __restrict__ Wthi,
                                                   const unsigned short* __restrict__ Wtlo,
                                                   float* __restrict__ C, int M) {
    __shared__ short wt[2][2][128][48];  // [dbuf][hi/lo][n][k(32)+pad16]
    const int t = threadIdx.x;
    const int m0 = blockIdx.x * 128;
    const int nb = blockIdx.y * 128;
    const int w = t >> 6, lane = t & 63;
    const int wr = w >> 1, wc = w & 1;
    const int lr = lane & 15, g = lane >> 4;

    f32x4 acc[4][4] = {};

    const int seg = t & 3, nr = t >> 2;
#define STAGE(BUF, KS)                                                              \
    {                                                                               \
        _Pragma("unroll") for (int rep = 0; rep < 2; ++rep) {                       \
            const int n = nr + rep * 64;                                            \
            const int gidx = (nb + n) * 256 + (KS) * 32 + seg * 8;                  \
            *(short8*)&wt[BUF][0][n][seg * 8] = *(const short8*)&Wthi[gidx];        \
            *(short8*)&wt[BUF][1][n][seg * 8] = *(const short8*)&Wtlo[gidx];        \
        }                                                                           \
    }

    STAGE(0, 0)
    int buf = 0;

    for (int ks = 0; ks < 8; ++ks) {
        __syncthreads();
        if (ks < 7) STAGE(buf ^ 1, ks + 1)

        short8 bh[4], bl[4];
#pragma unroll
        for (int ni = 0; ni < 4; ++ni) {
            const int n = wc * 64 + ni * 16 + lr;
            bh[ni] = *(const short8*)&wt[buf][0][n][g * 8];
            bl[ni] = *(const short8*)&wt[buf][1][n][g * 8];
        }

        short8 ah[4], al[4];
#pragma unroll
        for (int mi = 0; mi < 4; ++mi) {
            const int row = m0 + wr * 64 + mi * 16 + lr;
            float av[8] = {0.f, 0.f, 0.f, 0.f, 0.f, 0.f, 0.f, 0.f};
            if (row < M) {
                const float* ap = A + (size_t)row * 256 + ks * 32 + g * 8;
                const float4 p0 = *(const float4*)ap;
                const float4 p1 = *(const float4*)(ap + 4);
                av[0] = p0.x; av[1] = p0.y; av[2] = p0.z; av[3] = p0.w;
                av[4] = p1.x; av[5] = p1.y; av[6] = p1.z; av[7] = p1.w;
            }
#pragma unroll
            for (int i = 0; i < 8; ++i) {
                float v = RELU_IN ? fmaxf(av[i], 0.f) : av[i];
                unsigned short hi = f2bf(v);
                ah[mi][i] = (short)hi;
                al[mi][i] = (short)f2bf(v - bf2f(hi));
            }
        }

#pragma unroll
        for (int mi = 0; mi < 4; ++mi)
#pragma unroll
            for (int ni = 0; ni < 4; ++ni) {
                acc[mi][ni] = __builtin_amdgcn_mfma_f32_16x16x32_bf16(ah[mi], bh[ni], acc[mi][ni], 0, 0, 0);
                acc[mi][ni] = __builtin_amdgcn_mfma_f32_16x16x32_bf16(ah[mi], bl[ni], acc[mi][ni], 0, 0, 0);
                acc[mi][ni] = __builtin_amdgcn_mfma_f32_16x16x32_bf16(al[mi], bh[ni], acc[mi][ni], 0, 0, 0);
            }
        buf ^= 1;
    }
#undef STAGE

#pragma unroll
    for (int mi = 0; mi < 4; ++mi) {
        const int r0 = m0 + wr * 64 + mi * 16 + g * 4;
#pragma unroll
        for (int ni = 0; ni < 4; ++ni) {
            const int col = nb + wc * 64 + ni * 16 + lr;
#pragma unroll
            for (int r = 0; r < 4; ++r) {
                if (r0 + r < M) C[(size_t)(r0 + r) * 256 + col] = acc[mi][ni][r];
            }
        }
    }
}

// ================= aggregation: one wave per (node, feature-half) =================
__global__ __launch_bounds__(256) void k_aggregate(const float* __restrict__ h,
                                                   const int* __restrict__ row_start,
                                                   const unsigned int* __restrict__ csr,
                                                   const float* __restrict__ dinv,
                                                   const float* __restrict__ bias,
                                                   float* __restrict__ out) {
    const int wid = blockIdx.x * 4 + (threadIdx.x >> 6);
    const int node = wid >> 1;
    if (node >= N_NODES) return;
    const int half = wid & 1;
    const int lane = threadIdx.x & 63;
    const int fo = half * 128 + lane * 2;  // float2 per lane
    const float dd = dinv[node];
    const float wself = dd * dd;
    const float2 b = *(const float2*)(bias + fo);
    const float2 self = *(const float2*)(h + (size_t)node * NFEAT + fo);
    float accx = fmaf(self.x, wself, b.x);
    float accy = fmaf(self.y, wself, b.y);

    const int s0 = row_start[node], s1 = row_start[node + 1];
    const unsigned int* row = csr + s0;
    const int n = s1 - s0;
    int j = 0;
    for (; j + 7 < n; j += 8) {
        float2 v[8];
        float wn[8];
#pragma unroll
        for (int q = 0; q < 8; ++q) {
            const unsigned int e = row[j + q];
            v[q] = *(const float2*)(h + (size_t)(e & 0xffff) * NFEAT + fo);
            wn[q] = __half2float(__ushort_as_half((unsigned short)(e >> 16)));
        }
#pragma unroll
        for (int q = 0; q < 8; ++q) {
            accx = fmaf(v[q].x, wn[q], accx);
            accy = fmaf(v[q].y, wn[q], accy);
        }
    }
    for (; j < n; ++j) {
        const unsigned int e = row[j];
        const float2 v = *(const float2*)(h + (size_t)(e & 0xffff) * NFEAT + fo);
        const float wn = __half2float(__ushort_as_half((unsigned short)(e >> 16)));
        accx = fmaf(v.x, wn, accx);
        accy = fmaf(v.y, wn, accy);
    }
    *(float2*)(out + (size_t)node * NFEAT + fo) = make_float2(accx, accy);
}

// ================= pooling (batch sorted) + head =================
__global__ void k_zero_f(float* p, int n) {
    int i = blockIdx.x * 256 + threadIdx.x;
    if (i < n) p[i] = 0.f;
}

__global__ void k_pool(const float* __restrict__ h, const int* __restrict__ batch,
                       float* __restrict__ pooled) {
    const int NPB = 125;
    const int n0 = blockIdx.x * NPB;
    const int f = threadIdx.x;
    const int n1 = min(n0 + NPB, N_NODES);
    if (n0 >= N_NODES) return;
    int g = batch[n0];
    float acc = 0.f;
    for (int n = n0; n < n1; ++n) {
        const int bg = batch[n];
        if (bg != g) {
            unsafeAtomicAdd(&pooled[g * NFEAT + f], acc);
            acc = 0.f;
            g = bg;
        }
        acc += fmaxf(h[(size_t)n * NFEAT + f], 0.f);
    }
    unsafeAtomicAdd(&pooled[g * NFEAT + f], acc);
}

__global__ void k_final(const float* __restrict__ pooled, const float* __restrict__ Wout,
                        const float* __restrict__ bout, float* __restrict__ out) {
    const int g = blockIdx.x, t = threadIdx.x;
    float v = pooled[g * NFEAT + t] * Wout[t];
#pragma unroll
    for (int off = 32; off > 0; off >>= 1) v += __shfl_down(v, off, 64);
    __shared__ float sred[4];
    if ((t & 63) == 0) sred[t >> 6] = v;
    __syncthreads();
    if (t == 0) out[g] = sred[0] + sred[1] + sred[2] + sred[3] + bout[0];
}

extern "C" void kernel_launch(void* const* d_in, const int* in_sizes, int n_in,
                              void* d_out, int out_size, void* d_ws, size_t ws_size,
                              hipStream_t stream) {
    const float* x     = (const float*)d_in[0];
    const int*   ei    = (const int*)d_in[1];
    const int*   batch = (const int*)d_in[2];
    const float* W1    = (const float*)d_in[3];
    const float* b1    = (const float*)d_in[4];
    const float* W2    = (const float*)d_in[5];
    const float* b2    = (const float*)d_in[6];
    const float* Wout  = (const float*)d_in[7];
    const float* bout  = (const float*)d_in[8];
    float* out = (float*)d_out;

    const int* srcp = ei;
    const int* dstp = ei + NEDGE;

    float* buf0      = (float*)d_ws;                        // 12.8M f32
    float* buf1      = buf0 + (size_t)N_NODES * NFEAT;      // 12.8M f32
    float* dinv      = buf1 + (size_t)N_NODES * NFEAT;      // 50000
    float* pooled    = dinv + N_NODES;                      // 16384
    int*   cnt       = (int*)(pooled + NGRAPH * NFEAT);     // 50000 (doubles as cursor)
    int*   row_start = cnt + N_NODES;                       // 50001
    int*   bsum      = row_start + N_NODES + 2;             // 256
    unsigned int* csr = (unsigned int*)(bsum + 256);        // 800000
    unsigned short* w1hi = (unsigned short*)(csr + NEDGE);  // 65536 each
    unsigned short* w1lo = w1hi + 65536;
    unsigned short* w2hi = w1lo + 65536;
    unsigned short* w2lo = w2hi + 65536;

    const int nblk_edges = (NEDGE + 255) / 256;

    // ---- CSR build ----
    k_zero_int<<<NBLK_SCAN, 256, 0, stream>>>(cnt, N_NODES);
    k_count<<<nblk_edges, 256, 0, stream>>>(dstp, cnt);
    k_scan1<<<NBLK_SCAN, 256, 0, stream>>>(cnt, row_start, bsum);
    k_scan2<<<1, 256, 0, stream>>>(bsum);
    k_scan3<<<NBLK_SCAN, 256, 0, stream>>>(row_start, bsum, cnt, dinv);
    k_place<<<nblk_edges, 256, 0, stream>>>(srcp, dstp, cnt, dinv, csr);

    // ---- W decomposition ----
    k_prep_w<<<512, 256, 0, stream>>>(W1, W2, w1hi, w1lo, w2hi, w2lo);

    const dim3 ggrid((N_NODES + 127) / 128, 2);

    // ---- layer 1 ----
    k_gemm_mfma<false><<<ggrid, 256, 0, stream>>>(x, w1hi, w1lo, buf0, N_NODES);
    k_aggregate<<<(N_NODES * 2 + 3) / 4, 256, 0, stream>>>(buf0, row_start, csr, dinv, b1, buf1);

    // ---- layer 2 ----
    k_gemm_mfma<true><<<ggrid, 256, 0, stream>>>(buf1, w2hi, w2lo, buf0, N_NODES);
    k_aggregate<<<(N_NODES * 2 + 3) / 4, 256, 0, stream>>>(buf0, row_start, csr, dinv, b2, buf1);

    // ---- pooling + head ----
    k_zero_f<<<(NGRAPH * NFEAT + 255) / 256, 256, 0, stream>>>(pooled, NGRAPH * NFEAT);
    k_pool<<<400, 256, 0, stream>>>(buf1, batch, pooled);
    k_final<<<NGRAPH, 256, 0, stream>>>(pooled, Wout, bout, out);
}

// Round 5
// 357.643 us; speedup vs baseline: 15.7037x; 1.3331x over previous
//
#include <hip/hip_runtime.h>
#include <hip/hip_fp16.h>

#define N_NODES 50000
#define NFEAT   256
#define NGRAPH  64
#define NEDGE   800000
#define NBLK_SCAN 196  // ceil(50000/256)

typedef __attribute__((ext_vector_type(8))) short short8;
typedef __attribute__((ext_vector_type(4))) float f32x4;
struct alignas(8) US4 { unsigned short x, y, z, w; };

static __device__ __forceinline__ unsigned short f2bf(float f) {
    unsigned int u = __float_as_uint(f);
    unsigned int r = (u + 0x7fff + ((u >> 16) & 1)) >> 16;  // RTN-even
    return (unsigned short)r;
}
static __device__ __forceinline__ float bf2f(unsigned short b) {
    return __uint_as_float(((unsigned int)b) << 16);
}
static __device__ __forceinline__ float h2f(unsigned short u) {
    return __half2float(__ushort_as_half(u));
}

// ================= CSR build =================
__global__ void k_zero_int(int* p, int n) {
    int i = blockIdx.x * 256 + threadIdx.x;
    if (i < n) p[i] = 0;
}

__global__ void k_count(const int* __restrict__ dst, int* __restrict__ cnt) {
    int e = blockIdx.x * 256 + threadIdx.x;
    if (e < NEDGE) atomicAdd(&cnt[dst[e]], 1);
}

__global__ __launch_bounds__(256) void k_scan1(const int* __restrict__ cnt,
                                               int* __restrict__ row_start,
                                               int* __restrict__ bsum) {
    const int t = threadIdx.x, i = blockIdx.x * 256 + t;
    const int lane = t & 63, w = t >> 6;
    const int c = (i < N_NODES) ? cnt[i] : 0;
    int incl = c;
#pragma unroll
    for (int off = 1; off < 64; off <<= 1) {
        int u = __shfl_up(incl, off, 64);
        if (lane >= off) incl += u;
    }
    __shared__ int wtot[4];
    if (lane == 63) wtot[w] = incl;
    __syncthreads();
    int wbase = 0;
#pragma unroll
    for (int k = 0; k < 4; ++k) wbase += (k < w) ? wtot[k] : 0;
    if (i < N_NODES) row_start[i] = wbase + incl - c;
    if (t == 255) bsum[blockIdx.x] = wbase + incl;
}

__global__ __launch_bounds__(256) void k_scan2(int* __restrict__ bsum) {
    const int t = threadIdx.x, lane = t & 63, w = t >> 6;
    const int c = (t < NBLK_SCAN) ? bsum[t] : 0;
    int incl = c;
#pragma unroll
    for (int off = 1; off < 64; off <<= 1) {
        int u = __shfl_up(incl, off, 64);
        if (lane >= off) incl += u;
    }
    __shared__ int wtot[4];
    if (lane == 63) wtot[w] = incl;
    __syncthreads();
    int wbase = 0;
#pragma unroll
    for (int k = 0; k < 4; ++k) wbase += (k < w) ? wtot[k] : 0;
    if (t < NBLK_SCAN) bsum[t] = wbase + incl - c;
}

__global__ void k_scan3(int* __restrict__ row_start, const int* __restrict__ bsum,
                        int* __restrict__ cnt_cursor, float* __restrict__ dinv) {
    const int i = blockIdx.x * 256 + threadIdx.x;
    if (i >= N_NODES) return;
    const int c = cnt_cursor[i];
    const int start = row_start[i] + bsum[blockIdx.x];
    row_start[i] = start;
    cnt_cursor[i] = start;
    dinv[i] = rsqrtf((float)c + 1.0f);
    if (i == 0) row_start[N_NODES] = NEDGE;
}

__global__ void k_place(const int* __restrict__ src, const int* __restrict__ dst,
                        int* __restrict__ cursor, const float* __restrict__ dinv,
                        unsigned int* __restrict__ csr) {
    int e = blockIdx.x * 256 + threadIdx.x;
    if (e < NEDGE) {
        int s = src[e], d = dst[e];
        float norm = dinv[s] * dinv[d];
        int pos = atomicAdd(&cursor[d], 1);
        unsigned short hb = __half_as_ushort(__float2half(norm));
        csr[pos] = ((unsigned int)hb << 16) | (unsigned int)s;  // src < 65536 ok
    }
}

// ================= W prep: W[k][n] f32 -> Wt_hi/Wt_lo [n][k] bf16 =================
__global__ void k_prep_w(const float* __restrict__ W1, const float* __restrict__ W2,
                         unsigned short* __restrict__ w1hi, unsigned short* __restrict__ w1lo,
                         unsigned short* __restrict__ w2hi, unsigned short* __restrict__ w2lo) {
    const int l = blockIdx.x >> 8;
    const int idx = (blockIdx.x & 255) * 256 + threadIdx.x;
    const int n = idx >> 8, k = idx & 255;
    const float* W = l ? W2 : W1;
    unsigned short* whi = l ? w2hi : w1hi;
    unsigned short* wlo = l ? w2lo : w1lo;
    const float w = W[k * 256 + n];
    unsigned short hi = f2bf(w);
    unsigned short lo = f2bf(w - bf2f(hi));
    whi[n * 256 + k] = hi;
    wlo[n * 256 + k] = lo;
}

// ================= split x -> bf16 hi/lo planes (no relu) =================
__global__ void k_split_x(const float* __restrict__ x,
                          unsigned short* __restrict__ xhi, unsigned short* __restrict__ xlo) {
    int idx = blockIdx.x * 256 + threadIdx.x;  // per float4
    if (idx >= N_NODES * 64) return;
    const float4 v = ((const float4*)x)[idx];
    US4 hi, lo;
    hi.x = f2bf(v.x); lo.x = f2bf(v.x - bf2f(hi.x));
    hi.y = f2bf(v.y); lo.y = f2bf(v.y - bf2f(hi.y));
    hi.z = f2bf(v.z); lo.z = f2bf(v.z - bf2f(hi.z));
    hi.w = f2bf(v.w); lo.w = f2bf(v.w - bf2f(hi.w));
    ((US4*)xhi)[idx] = hi;
    ((US4*)xlo)[idx] = lo;
}

// ================= MFMA split-bf16 GEMM: Ch[M,256](fp16) = (Ahi+Alo) @ (Whi+Wlo) ========
__global__ __launch_bounds__(256) void k_gemm_mfma(const unsigned short* __restrict__ Ahi,
                                                   const unsigned short* __restrict__ Alo,
                                                   const unsigned short* __restrict__ Wthi,
                                                   const unsigned short* __restrict__ Wtlo,
                                                   unsigned short* __restrict__ Ch, int M) {
    __shared__ short wt[2][2][128][48];  // [dbuf][hi/lo][n][k(32)+pad16]
    const int t = threadIdx.x;
    const int m0 = blockIdx.x * 128;
    const int nb = blockIdx.y * 128;
    const int w = t >> 6, lane = t & 63;
    const int wr = w >> 1, wc = w & 1;
    const int lr = lane & 15, g = lane >> 4;

    f32x4 acc[4][4] = {};

    const int seg = t & 3, nr = t >> 2;
#define STAGE(BUF, KS)                                                              \
    {                                                                               \
        _Pragma("unroll") for (int rep = 0; rep < 2; ++rep) {                       \
            const int n = nr + rep * 64;                                            \
            const int gidx = (nb + n) * 256 + (KS) * 32 + seg * 8;                  \
            *(short8*)&wt[BUF][0][n][seg * 8] = *(const short8*)&Wthi[gidx];        \
            *(short8*)&wt[BUF][1][n][seg * 8] = *(const short8*)&Wtlo[gidx];        \
        }                                                                           \
    }

    STAGE(0, 0)
    int buf = 0;

    for (int ks = 0; ks < 8; ++ks) {
        __syncthreads();
        if (ks < 7) STAGE(buf ^ 1, ks + 1)

        short8 bh[4], bl[4];
#pragma unroll
        for (int ni = 0; ni < 4; ++ni) {
            const int n = wc * 64 + ni * 16 + lr;
            bh[ni] = *(const short8*)&wt[buf][0][n][g * 8];
            bl[ni] = *(const short8*)&wt[buf][1][n][g * 8];
        }

        short8 ah[4], al[4];
#pragma unroll
        for (int mi = 0; mi < 4; ++mi) {
            const int row = m0 + wr * 64 + mi * 16 + lr;
            if (row < M) {
                const size_t o = (size_t)row * 256 + ks * 32 + g * 8;
                ah[mi] = *(const short8*)&Ahi[o];
                al[mi] = *(const short8*)&Alo[o];
            } else {
                ah[mi] = (short8)0;
                al[mi] = (short8)0;
            }
        }

#pragma unroll
        for (int mi = 0; mi < 4; ++mi)
#pragma unroll
            for (int ni = 0; ni < 4; ++ni) {
                acc[mi][ni] = __builtin_amdgcn_mfma_f32_16x16x32_bf16(ah[mi], bh[ni], acc[mi][ni], 0, 0, 0);
                acc[mi][ni] = __builtin_amdgcn_mfma_f32_16x16x32_bf16(ah[mi], bl[ni], acc[mi][ni], 0, 0, 0);
                acc[mi][ni] = __builtin_amdgcn_mfma_f32_16x16x32_bf16(al[mi], bh[ni], acc[mi][ni], 0, 0, 0);
            }
        buf ^= 1;
    }
#undef STAGE

#pragma unroll
    for (int mi = 0; mi < 4; ++mi) {
        const int r0 = m0 + wr * 64 + mi * 16 + g * 4;
#pragma unroll
        for (int ni = 0; ni < 4; ++ni) {
            const int col = nb + wc * 64 + ni * 16 + lr;
#pragma unroll
            for (int r = 0; r < 4; ++r) {
                if (r0 + r < M)
                    Ch[(size_t)(r0 + r) * 256 + col] = __half_as_ushort(__float2half(acc[mi][ni][r]));
            }
        }
    }
}

// ================= aggregation: one wave per node; fp16 gather; relu'd hi/lo out ========
__global__ __launch_bounds__(256) void k_aggregate(const unsigned short* __restrict__ h16,
                                                   const int* __restrict__ row_start,
                                                   const unsigned int* __restrict__ csr,
                                                   const float* __restrict__ dinv,
                                                   const float* __restrict__ bias,
                                                   unsigned short* __restrict__ Phi,
                                                   unsigned short* __restrict__ Plo) {
    const int node = blockIdx.x * 4 + (threadIdx.x >> 6);
    if (node >= N_NODES) return;
    const int lane = threadIdx.x & 63;
    const int fo = lane * 4;
    const float dd = dinv[node];
    const float wself = dd * dd;
    const float4 b = *(const float4*)(bias + fo);
    const US4 sh = *(const US4*)(h16 + (size_t)node * 256 + fo);
    float a0 = fmaf(h2f(sh.x), wself, b.x);
    float a1 = fmaf(h2f(sh.y), wself, b.y);
    float a2 = fmaf(h2f(sh.z), wself, b.z);
    float a3 = fmaf(h2f(sh.w), wself, b.w);

    const int s0 = row_start[node], s1 = row_start[node + 1];
    const unsigned int* row = csr + s0;
    const int n = s1 - s0;
    int j = 0;
    for (; j + 7 < n; j += 8) {
        US4 v[8];
        float wn[8];
#pragma unroll
        for (int q = 0; q < 8; ++q) {
            const unsigned int e = row[j + q];
            v[q] = *(const US4*)(h16 + (size_t)(e & 0xffff) * 256 + fo);
            wn[q] = h2f((unsigned short)(e >> 16));
        }
#pragma unroll
        for (int q = 0; q < 8; ++q) {
            a0 = fmaf(h2f(v[q].x), wn[q], a0);
            a1 = fmaf(h2f(v[q].y), wn[q], a1);
            a2 = fmaf(h2f(v[q].z), wn[q], a2);
            a3 = fmaf(h2f(v[q].w), wn[q], a3);
        }
    }
    for (; j < n; ++j) {
        const unsigned int e = row[j];
        const US4 v = *(const US4*)(h16 + (size_t)(e & 0xffff) * 256 + fo);
        const float wq = h2f((unsigned short)(e >> 16));
        a0 = fmaf(h2f(v.x), wq, a0);
        a1 = fmaf(h2f(v.y), wq, a1);
        a2 = fmaf(h2f(v.z), wq, a2);
        a3 = fmaf(h2f(v.w), wq, a3);
    }

    // relu + split to bf16 hi/lo planes
    a0 = fmaxf(a0, 0.f); a1 = fmaxf(a1, 0.f); a2 = fmaxf(a2, 0.f); a3 = fmaxf(a3, 0.f);
    US4 hi, lo;
    hi.x = f2bf(a0); lo.x = f2bf(a0 - bf2f(hi.x));
    hi.y = f2bf(a1); lo.y = f2bf(a1 - bf2f(hi.y));
    hi.z = f2bf(a2); lo.z = f2bf(a2 - bf2f(hi.z));
    hi.w = f2bf(a3); lo.w = f2bf(a3 - bf2f(hi.w));
    *(US4*)(Phi + (size_t)node * 256 + fo) = hi;
    *(US4*)(Plo + (size_t)node * 256 + fo) = lo;
}

// ================= pooling (batch sorted): pooled[g] += (hi+lo) =================
__global__ void k_zero_f(float* p, int n) {
    int i = blockIdx.x * 256 + threadIdx.x;
    if (i < n) p[i] = 0.f;
}

// 625 blocks x 256 thr; 2 strips/block x 128 thr; strip = 40 nodes; thread covers 2 feats
__global__ void k_pool(const unsigned short* __restrict__ Phi,
                       const unsigned short* __restrict__ Plo,
                       const int* __restrict__ batch, float* __restrict__ pooled) {
    const int strip = blockIdx.x * 2 + (threadIdx.x >> 7);
    const int tf = threadIdx.x & 127;
    const int n0 = strip * 40, n1 = n0 + 40;
    int g = batch[n0];
    float ax = 0.f, ay = 0.f;
    for (int n = n0; n < n1; ++n) {
        const int bg = batch[n];
        if (bg != g) {
            unsafeAtomicAdd(&pooled[g * NFEAT + tf * 2], ax);
            unsafeAtomicAdd(&pooled[g * NFEAT + tf * 2 + 1], ay);
            ax = ay = 0.f;
            g = bg;
        }
        const unsigned int hu = *(const unsigned int*)(Phi + (size_t)n * 256 + tf * 2);
        const unsigned int lu = *(const unsigned int*)(Plo + (size_t)n * 256 + tf * 2);
        ax += bf2f((unsigned short)(hu & 0xffff)) + bf2f((unsigned short)(lu & 0xffff));
        ay += bf2f((unsigned short)(hu >> 16)) + bf2f((unsigned short)(lu >> 16));
    }
    unsafeAtomicAdd(&pooled[g * NFEAT + tf * 2], ax);
    unsafeAtomicAdd(&pooled[g * NFEAT + tf * 2 + 1], ay);
}

__global__ void k_final(const float* __restrict__ pooled, const float* __restrict__ Wout,
                        const float* __restrict__ bout, float* __restrict__ out) {
    const int g = blockIdx.x, t = threadIdx.x;
    float v = pooled[g * NFEAT + t] * Wout[t];
#pragma unroll
    for (int off = 32; off > 0; off >>= 1) v += __shfl_down(v, off, 64);
    __shared__ float sred[4];
    if ((t & 63) == 0) sred[t >> 6] = v;
    __syncthreads();
    if (t == 0) out[g] = sred[0] + sred[1] + sred[2] + sred[3] + bout[0];
}

extern "C" void kernel_launch(void* const* d_in, const int* in_sizes, int n_in,
                              void* d_out, int out_size, void* d_ws, size_t ws_size,
                              hipStream_t stream) {
    const float* x     = (const float*)d_in[0];
    const int*   ei    = (const int*)d_in[1];
    const int*   batch = (const int*)d_in[2];
    const float* W1    = (const float*)d_in[3];
    const float* b1    = (const float*)d_in[4];
    const float* W2    = (const float*)d_in[5];
    const float* b2    = (const float*)d_in[6];
    const float* Wout  = (const float*)d_in[7];
    const float* bout  = (const float*)d_in[8];
    float* out = (float*)d_out;

    const int* srcp = ei;
    const int* dstp = ei + NEDGE;

    const size_t NE = (size_t)N_NODES * NFEAT;  // 12.8M elements
    unsigned short* Phi = (unsigned short*)d_ws;           // 12.8M ushort
    unsigned short* Plo = Phi + NE;                        // 12.8M ushort
    unsigned short* h16 = Plo + NE;                        // 12.8M ushort
    float* dinv      = (float*)(h16 + NE);                 // 50000
    float* pooled    = dinv + N_NODES;                     // 16384
    int*   cnt       = (int*)(pooled + NGRAPH * NFEAT);    // 50000 (doubles as cursor)
    int*   row_start = cnt + N_NODES;                      // 50001
    int*   bsum      = row_start + N_NODES + 3;            // 256
    unsigned int* csr = (unsigned int*)(bsum + 256);       // 800000
    unsigned short* w1hi = (unsigned short*)(csr + NEDGE); // 65536 each
    unsigned short* w1lo = w1hi + 65536;
    unsigned short* w2hi = w1lo + 65536;
    unsigned short* w2lo = w2hi + 65536;

    const int nblk_edges = (NEDGE + 255) / 256;

    // ---- CSR build ----
    k_zero_int<<<NBLK_SCAN, 256, 0, stream>>>(cnt, N_NODES);
    k_count<<<nblk_edges, 256, 0, stream>>>(dstp, cnt);
    k_scan1<<<NBLK_SCAN, 256, 0, stream>>>(cnt, row_start, bsum);
    k_scan2<<<1, 256, 0, stream>>>(bsum);
    k_scan3<<<NBLK_SCAN, 256, 0, stream>>>(row_start, bsum, cnt, dinv);
    k_place<<<nblk_edges, 256, 0, stream>>>(srcp, dstp, cnt, dinv, csr);

    // ---- weight + input prep ----
    k_prep_w<<<512, 256, 0, stream>>>(W1, W2, w1hi, w1lo, w2hi, w2lo);
    k_split_x<<<(N_NODES * 64 + 255) / 256, 256, 0, stream>>>(x, Phi, Plo);

    const dim3 ggrid((N_NODES + 127) / 128, 2);

    // ---- layer 1 ----
    k_gemm_mfma<<<ggrid, 256, 0, stream>>>(Phi, Plo, w1hi, w1lo, h16, N_NODES);
    k_aggregate<<<(N_NODES + 3) / 4, 256, 0, stream>>>(h16, row_start, csr, dinv, b1, Phi, Plo);

    // ---- layer 2 ----
    k_gemm_mfma<<<ggrid, 256, 0, stream>>>(Phi, Plo, w2hi, w2lo, h16, N_NODES);
    k_aggregate<<<(N_NODES + 3) / 4, 256, 0, stream>>>(h16, row_start, csr, dinv, b2, Phi, Plo);

    // ---- pooling + head ----
    k_zero_f<<<(NGRAPH * NFEAT + 255) / 256, 256, 0, stream>>>(pooled, NGRAPH * NFEAT);
    k_pool<<<625, 256, 0, stream>>>(Phi, Plo, batch, pooled);
    k_final<<<NGRAPH, 256, 0, stream>>>(pooled, Wout, bout, out);
}

// Round 6
// 349.395 us; speedup vs baseline: 16.0744x; 1.0236x over previous
//
#include <hip/hip_runtime.h>
#include <hip/hip_fp16.h>

#define N_NODES 50000
#define NFEAT   256
#define NGRAPH  64
#define NEDGE   800000
#define NBLK_SCAN 196  // ceil(50000/256)

typedef __attribute__((ext_vector_type(8))) short short8;
typedef __attribute__((ext_vector_type(4))) float f32x4;
struct alignas(8) US4 { unsigned short x, y, z, w; };

static __device__ __forceinline__ unsigned short f2bf(float f) {
    unsigned int u = __float_as_uint(f);
    unsigned int r = (u + 0x7fff + ((u >> 16) & 1)) >> 16;  // RTN-even
    return (unsigned short)r;
}
static __device__ __forceinline__ float bf2f(unsigned short b) {
    return __uint_as_float(((unsigned int)b) << 16);
}
static __device__ __forceinline__ float h2f(unsigned short u) {
    return __half2float(__ushort_as_half(u));
}
static __device__ __forceinline__ unsigned short f2h(float f) {
    return __half_as_ushort(__float2half(f));
}

// ================= CSR build =================
__global__ void k_zero_int(int* p, int n) {
    int i = blockIdx.x * 256 + threadIdx.x;
    if (i < n) p[i] = 0;
}

__global__ void k_count(const int* __restrict__ dst, int* __restrict__ cnt) {
    int e = blockIdx.x * 256 + threadIdx.x;
    if (e < NEDGE) atomicAdd(&cnt[dst[e]], 1);
}

__global__ __launch_bounds__(256) void k_scan1(const int* __restrict__ cnt,
                                               int* __restrict__ row_start,
                                               int* __restrict__ bsum) {
    const int t = threadIdx.x, i = blockIdx.x * 256 + t;
    const int lane = t & 63, w = t >> 6;
    const int c = (i < N_NODES) ? cnt[i] : 0;
    int incl = c;
#pragma unroll
    for (int off = 1; off < 64; off <<= 1) {
        int u = __shfl_up(incl, off, 64);
        if (lane >= off) incl += u;
    }
    __shared__ int wtot[4];
    if (lane == 63) wtot[w] = incl;
    __syncthreads();
    int wbase = 0;
#pragma unroll
    for (int k = 0; k < 4; ++k) wbase += (k < w) ? wtot[k] : 0;
    if (i < N_NODES) row_start[i] = wbase + incl - c;
    if (t == 255) bsum[blockIdx.x] = wbase + incl;
}

__global__ __launch_bounds__(256) void k_scan2(int* __restrict__ bsum) {
    const int t = threadIdx.x, lane = t & 63, w = t >> 6;
    const int c = (t < NBLK_SCAN) ? bsum[t] : 0;
    int incl = c;
#pragma unroll
    for (int off = 1; off < 64; off <<= 1) {
        int u = __shfl_up(incl, off, 64);
        if (lane >= off) incl += u;
    }
    __shared__ int wtot[4];
    if (lane == 63) wtot[w] = incl;
    __syncthreads();
    int wbase = 0;
#pragma unroll
    for (int k = 0; k < 4; ++k) wbase += (k < w) ? wtot[k] : 0;
    if (t < NBLK_SCAN) bsum[t] = wbase + incl - c;
}

__global__ void k_scan3(int* __restrict__ row_start, const int* __restrict__ bsum,
                        int* __restrict__ cnt_cursor, float* __restrict__ dinv) {
    const int i = blockIdx.x * 256 + threadIdx.x;
    if (i >= N_NODES) return;
    const int c = cnt_cursor[i];
    const int start = row_start[i] + bsum[blockIdx.x];
    row_start[i] = start;
    cnt_cursor[i] = start;
    dinv[i] = rsqrtf((float)c + 1.0f);
    if (i == 0) row_start[N_NODES] = NEDGE;
}

__global__ void k_place(const int* __restrict__ src, const int* __restrict__ dst,
                        int* __restrict__ cursor, const float* __restrict__ dinv,
                        unsigned int* __restrict__ csr) {
    int e = blockIdx.x * 256 + threadIdx.x;
    if (e < NEDGE) {
        int s = src[e], d = dst[e];
        float norm = dinv[s] * dinv[d];
        int pos = atomicAdd(&cursor[d], 1);
        csr[pos] = ((unsigned int)__half_as_ushort(__float2half(norm)) << 16) | (unsigned int)s;
    }
}

// ================= W prep: W[k][n] f32 -> Wt_hi/Wt_lo [n][k] bf16 =================
__global__ void k_prep_w(const float* __restrict__ W1, const float* __restrict__ W2,
                         unsigned short* __restrict__ w1hi, unsigned short* __restrict__ w1lo,
                         unsigned short* __restrict__ w2hi, unsigned short* __restrict__ w2lo) {
    const int l = blockIdx.x >> 8;
    const int idx = (blockIdx.x & 255) * 256 + threadIdx.x;
    const int n = idx >> 8, k = idx & 255;
    const float* W = l ? W2 : W1;
    unsigned short* whi = l ? w2hi : w1hi;
    unsigned short* wlo = l ? w2lo : w1lo;
    const float w = W[k * 256 + n];
    unsigned short hi = f2bf(w);
    unsigned short lo = f2bf(w - bf2f(hi));
    whi[n * 256 + k] = hi;
    wlo[n * 256 + k] = lo;
}

// ================= MFMA split-bf16 GEMM =================
// C (fp16, [half][node][128]) = A @ W.  A either f32 (split inline) or pre-split planes.
template <bool AF32>
__global__ __launch_bounds__(256) void k_gemm_mfma(const float* __restrict__ Af,
                                                   const unsigned short* __restrict__ Ahi,
                                                   const unsigned short* __restrict__ Alo,
                                                   const unsigned short* __restrict__ Wthi,
                                                   const unsigned short* __restrict__ Wtlo,
                                                   unsigned short* __restrict__ Ch, int M) {
    __shared__ short wt[2][2][128][48];  // [dbuf][hi/lo][n][k(32)+pad16]
    const int t = threadIdx.x;
    const int m0 = blockIdx.x * 128;
    const int nb = blockIdx.y * 128;
    const int w = t >> 6, lane = t & 63;
    const int wr = w >> 1, wc = w & 1;
    const int lr = lane & 15, g = lane >> 4;

    f32x4 acc[4][4] = {};

    const int seg = t & 3, nr = t >> 2;
#define STAGE(BUF, KS)                                                              \
    {                                                                               \
        _Pragma("unroll") for (int rep = 0; rep < 2; ++rep) {                       \
            const int n = nr + rep * 64;                                            \
            const int gidx = (nb + n) * 256 + (KS) * 32 + seg * 8;                  \
            *(short8*)&wt[BUF][0][n][seg * 8] = *(const short8*)&Wthi[gidx];        \
            *(short8*)&wt[BUF][1][n][seg * 8] = *(const short8*)&Wtlo[gidx];        \
        }                                                                           \
    }

    STAGE(0, 0)
    int buf = 0;

    for (int ks = 0; ks < 8; ++ks) {
        __syncthreads();
        if (ks < 7) STAGE(buf ^ 1, ks + 1)

        short8 bh[4], bl[4];
#pragma unroll
        for (int ni = 0; ni < 4; ++ni) {
            const int n = wc * 64 + ni * 16 + lr;
            bh[ni] = *(const short8*)&wt[buf][0][n][g * 8];
            bl[ni] = *(const short8*)&wt[buf][1][n][g * 8];
        }

        short8 ah[4], al[4];
#pragma unroll
        for (int mi = 0; mi < 4; ++mi) {
            const int row = m0 + wr * 64 + mi * 16 + lr;
            if (AF32) {
                float av[8] = {0.f, 0.f, 0.f, 0.f, 0.f, 0.f, 0.f, 0.f};
                if (row < M) {
                    const float* ap = Af + (size_t)row * 256 + ks * 32 + g * 8;
                    const float4 p0 = *(const float4*)ap;
                    const float4 p1 = *(const float4*)(ap + 4);
                    av[0] = p0.x; av[1] = p0.y; av[2] = p0.z; av[3] = p0.w;
                    av[4] = p1.x; av[5] = p1.y; av[6] = p1.z; av[7] = p1.w;
                }
#pragma unroll
                for (int i = 0; i < 8; ++i) {
                    unsigned short hi = f2bf(av[i]);
                    ah[mi][i] = (short)hi;
                    al[mi][i] = (short)f2bf(av[i] - bf2f(hi));
                }
            } else {
                if (row < M) {
                    const size_t o = (size_t)row * 256 + ks * 32 + g * 8;
                    ah[mi] = *(const short8*)&Ahi[o];
                    al[mi] = *(const short8*)&Alo[o];
                } else {
                    ah[mi] = (short8)0;
                    al[mi] = (short8)0;
                }
            }
        }

#pragma unroll
        for (int mi = 0; mi < 4; ++mi)
#pragma unroll
            for (int ni = 0; ni < 4; ++ni) {
                acc[mi][ni] = __builtin_amdgcn_mfma_f32_16x16x32_bf16(ah[mi], bh[ni], acc[mi][ni], 0, 0, 0);
                acc[mi][ni] = __builtin_amdgcn_mfma_f32_16x16x32_bf16(ah[mi], bl[ni], acc[mi][ni], 0, 0, 0);
                acc[mi][ni] = __builtin_amdgcn_mfma_f32_16x16x32_bf16(al[mi], bh[ni], acc[mi][ni], 0, 0, 0);
            }
        buf ^= 1;
    }
#undef STAGE

    // write fp16 into [half = blockIdx.y][node][128]
    unsigned short* Chh = Ch + (size_t)blockIdx.y * N_NODES * 128;
#pragma unroll
    for (int mi = 0; mi < 4; ++mi) {
        const int r0 = m0 + wr * 64 + mi * 16 + g * 4;
#pragma unroll
        for (int ni = 0; ni < 4; ++ni) {
            const int c = wc * 64 + ni * 16 + lr;  // 0..127
#pragma unroll
            for (int r = 0; r < 4; ++r) {
                if (r0 + r < M) Chh[(size_t)(r0 + r) * 128 + c] = f2h(acc[mi][ni][r]);
            }
        }
    }
}

// ================= aggregation: wave per (node, feature-half); 2 edges/wave ===========
// MODE 0: write relu'd bf16 hi/lo planes [node][256] (feeds GEMM-2)
// MODE 1: write relu'd fp16 [node][256]  (feeds pooling)
template <int MODE>
__global__ __launch_bounds__(256) void k_aggregate(const unsigned short* __restrict__ h16,
                                                   const int* __restrict__ row_start,
                                                   const unsigned int* __restrict__ csr,
                                                   const float* __restrict__ dinv,
                                                   const float* __restrict__ bias,
                                                   unsigned short* __restrict__ out0,
                                                   unsigned short* __restrict__ out1) {
    const int wid = blockIdx.x * 4 + (threadIdx.x >> 6);
    if (wid >= 2 * N_NODES) return;
    const int half = (wid >= N_NODES) ? 1 : 0;            // all half-0 wids first
    const int node = wid - half * N_NODES;
    const int lane = threadIdx.x & 63;
    const int sub = lane >> 5, fl = lane & 31;
    const unsigned short* hh = h16 + (size_t)half * N_NODES * 128;

    float a0 = 0.f, a1 = 0.f, a2 = 0.f, a3 = 0.f;
    const int s0 = row_start[node], s1 = row_start[node + 1];
    const unsigned int* row = csr + s0;
    const int n = s1 - s0;
    int j = 0;
    for (; j + 7 < n; j += 8) {
        US4 v[4];
        float wn[4];
#pragma unroll
        for (int q = 0; q < 4; ++q) {
            const unsigned int e = row[j + q * 2 + sub];
            v[q] = *(const US4*)(hh + (size_t)(e & 0xffff) * 128 + fl * 4);
            wn[q] = h2f((unsigned short)(e >> 16));
        }
#pragma unroll
        for (int q = 0; q < 4; ++q) {
            a0 = fmaf(h2f(v[q].x), wn[q], a0);
            a1 = fmaf(h2f(v[q].y), wn[q], a1);
            a2 = fmaf(h2f(v[q].z), wn[q], a2);
            a3 = fmaf(h2f(v[q].w), wn[q], a3);
        }
    }
    for (; j < n; j += 2) {
        const int ep = j + sub;
        if (ep < n) {
            const unsigned int e = row[ep];
            const US4 v = *(const US4*)(hh + (size_t)(e & 0xffff) * 128 + fl * 4);
            const float wq = h2f((unsigned short)(e >> 16));
            a0 = fmaf(h2f(v.x), wq, a0);
            a1 = fmaf(h2f(v.y), wq, a1);
            a2 = fmaf(h2f(v.z), wq, a2);
            a3 = fmaf(h2f(v.w), wq, a3);
        }
    }
    // fold lanes 32-63 (second edge of each pair) into lanes 0-31
    a0 += __shfl_xor(a0, 32, 64);
    a1 += __shfl_xor(a1, 32, 64);
    a2 += __shfl_xor(a2, 32, 64);
    a3 += __shfl_xor(a3, 32, 64);

    if (sub == 0) {
        const int gf = half * 128 + fl * 4;
        const float dd = dinv[node];
        const float ws = dd * dd;
        const US4 sh = *(const US4*)(hh + (size_t)node * 128 + fl * 4);
        const float4 b = *(const float4*)(bias + gf);
        a0 = fmaxf(fmaf(h2f(sh.x), ws, a0) + b.x, 0.f);
        a1 = fmaxf(fmaf(h2f(sh.y), ws, a1) + b.y, 0.f);
        a2 = fmaxf(fmaf(h2f(sh.z), ws, a2) + b.z, 0.f);
        a3 = fmaxf(fmaf(h2f(sh.w), ws, a3) + b.w, 0.f);
        if (MODE == 0) {
            US4 hi, lo;
            hi.x = f2bf(a0); lo.x = f2bf(a0 - bf2f(hi.x));
            hi.y = f2bf(a1); lo.y = f2bf(a1 - bf2f(hi.y));
            hi.z = f2bf(a2); lo.z = f2bf(a2 - bf2f(hi.z));
            hi.w = f2bf(a3); lo.w = f2bf(a3 - bf2f(hi.w));
            *(US4*)(out0 + (size_t)node * 256 + gf) = hi;
            *(US4*)(out1 + (size_t)node * 256 + gf) = lo;
        } else {
            US4 o;
            o.x = f2h(a0); o.y = f2h(a1); o.z = f2h(a2); o.w = f2h(a3);
            *(US4*)(out0 + (size_t)node * 256 + gf) = o;
        }
    }
}

// ================= pooling (batch sorted) + head =================
__global__ void k_zero_f(float* p, int n) {
    int i = blockIdx.x * 256 + threadIdx.x;
    if (i < n) p[i] = 0.f;
}

// 625 blocks x 256 thr; 2 strips/block x 128 thr; strip = 40 nodes; thread = 2 feats
__global__ void k_pool(const unsigned short* __restrict__ h2, const int* __restrict__ batch,
                       float* __restrict__ pooled) {
    const int strip = blockIdx.x * 2 + (threadIdx.x >> 7);
    const int tf = threadIdx.x & 127;
    const int n0 = strip * 40, n1 = n0 + 40;
    int g = batch[n0];
    float ax = 0.f, ay = 0.f;
    for (int n = n0; n < n1; ++n) {
        const int bg = batch[n];
        if (bg != g) {
            unsafeAtomicAdd(&pooled[g * NFEAT + tf * 2], ax);
            unsafeAtomicAdd(&pooled[g * NFEAT + tf * 2 + 1], ay);
            ax = ay = 0.f;
            g = bg;
        }
        const unsigned int u = *(const unsigned int*)(h2 + (size_t)n * 256 + tf * 2);
        ax += h2f((unsigned short)(u & 0xffff));
        ay += h2f((unsigned short)(u >> 16));
    }
    unsafeAtomicAdd(&pooled[g * NFEAT + tf * 2], ax);
    unsafeAtomicAdd(&pooled[g * NFEAT + tf * 2 + 1], ay);
}

__global__ void k_final(const float* __restrict__ pooled, const float* __restrict__ Wout,
                        const float* __restrict__ bout, float* __restrict__ out) {
    const int g = blockIdx.x, t = threadIdx.x;
    float v = pooled[g * NFEAT + t] * Wout[t];
#pragma unroll
    for (int off = 32; off > 0; off >>= 1) v += __shfl_down(v, off, 64);
    __shared__ float sred[4];
    if ((t & 63) == 0) sred[t >> 6] = v;
    __syncthreads();
    if (t == 0) out[g] = sred[0] + sred[1] + sred[2] + sred[3] + bout[0];
}

extern "C" void kernel_launch(void* const* d_in, const int* in_sizes, int n_in,
                              void* d_out, int out_size, void* d_ws, size_t ws_size,
                              hipStream_t stream) {
    const float* x     = (const float*)d_in[0];
    const int*   ei    = (const int*)d_in[1];
    const int*   batch = (const int*)d_in[2];
    const float* W1    = (const float*)d_in[3];
    const float* b1    = (const float*)d_in[4];
    const float* W2    = (const float*)d_in[5];
    const float* b2    = (const float*)d_in[6];
    const float* Wout  = (const float*)d_in[7];
    const float* bout  = (const float*)d_in[8];
    float* out = (float*)d_out;

    const int* srcp = ei;
    const int* dstp = ei + NEDGE;

    const size_t NE = (size_t)N_NODES * NFEAT;  // 12.8M elements
    unsigned short* Phi = (unsigned short*)d_ws;           // [N][256] bf16-hi (also h2out alias)
    unsigned short* Plo = Phi + NE;                        // [N][256] bf16-lo
    unsigned short* h16 = Plo + NE;                        // [2][N][128] fp16 GEMM out
    float* dinv      = (float*)(h16 + NE);                 // 50000
    float* pooled    = dinv + N_NODES;                     // 16384
    int*   cnt       = (int*)(pooled + NGRAPH * NFEAT);    // 50000 (doubles as cursor)
    int*   row_start = cnt + N_NODES;                      // 50001
    int*   bsum      = row_start + N_NODES + 3;            // 256
    unsigned int* csr = (unsigned int*)(bsum + 256);       // 800000
    unsigned short* w1hi = (unsigned short*)(csr + NEDGE); // 65536 each
    unsigned short* w1lo = w1hi + 65536;
    unsigned short* w2hi = w1lo + 65536;
    unsigned short* w2lo = w2hi + 65536;

    const int nblk_edges = (NEDGE + 255) / 256;

    // ---- CSR build ----
    k_zero_int<<<NBLK_SCAN, 256, 0, stream>>>(cnt, N_NODES);
    k_count<<<nblk_edges, 256, 0, stream>>>(dstp, cnt);
    k_scan1<<<NBLK_SCAN, 256, 0, stream>>>(cnt, row_start, bsum);
    k_scan2<<<1, 256, 0, stream>>>(bsum);
    k_scan3<<<NBLK_SCAN, 256, 0, stream>>>(row_start, bsum, cnt, dinv);
    k_place<<<nblk_edges, 256, 0, stream>>>(srcp, dstp, cnt, dinv, csr);

    // ---- weight prep ----
    k_prep_w<<<512, 256, 0, stream>>>(W1, W2, w1hi, w1lo, w2hi, w2lo);

    const dim3 ggrid((N_NODES + 127) / 128, 2);
    const int agg_grid = (2 * N_NODES + 3) / 4;  // 25000

    // ---- layer 1 (x split fused into GEMM) ----
    k_gemm_mfma<true><<<ggrid, 256, 0, stream>>>(x, nullptr, nullptr, w1hi, w1lo, h16, N_NODES);
    k_aggregate<0><<<agg_grid, 256, 0, stream>>>(h16, row_start, csr, dinv, b1, Phi, Plo);

    // ---- layer 2 ----
    k_gemm_mfma<false><<<ggrid, 256, 0, stream>>>(nullptr, Phi, Plo, w2hi, w2lo, h16, N_NODES);
    // Phi is free after GEMM-2; reuse it as the fp16 relu'd layer-2 output
    k_aggregate<1><<<agg_grid, 256, 0, stream>>>(h16, row_start, csr, dinv, b2, Phi, nullptr);

    // ---- pooling + head ----
    k_zero_f<<<(NGRAPH * NFEAT + 255) / 256, 256, 0, stream>>>(pooled, NGRAPH * NFEAT);
    k_pool<<<625, 256, 0, stream>>>(Phi, batch, pooled);
    k_final<<<NGRAPH, 256, 0, stream>>>(pooled, Wout, bout, out);
}